// Round 9
// baseline (186.685 us; speedup 1.0000x reference)
//
#include <hip/hip_runtime.h>

// Problem constants (from reference)
#define N1C 50000
#define N2C 50000
#define NNC 16
#define NIC 64
#define NDC 128
#define QB  16       // queries per block (16 queries x 16 neighbors = 256 rows)
#define MR  256      // QB*NN rows per block
#define FELEMS (N1C * NIC)   // 3.2M elements per feature array

#define LOG2E 1.4426950408889634f
#define LN2   0.6931471805599453f

typedef __bf16 bf16x8 __attribute__((ext_vector_type(8)));
typedef float f32x4 __attribute__((ext_vector_type(4)));
typedef unsigned u32x4 __attribute__((ext_vector_type(4)));
typedef unsigned u32x2 __attribute__((ext_vector_type(2)));
typedef __fp16 f16x4 __attribute__((ext_vector_type(4)));
typedef __fp16 f16x2 __attribute__((ext_vector_type(2)));

#if defined(__has_builtin)
#if __has_builtin(__builtin_amdgcn_cvt_pk_bf16_f32)
#define HAVE_PK_BF16 1
#endif
#if __has_builtin(__builtin_amdgcn_permlane32_swap)
#define HAVE_PL32 1
#endif
#if __has_builtin(__builtin_amdgcn_mfma_f32_16x16x16f16) && __has_builtin(__builtin_amdgcn_cvt_pkrtz)
#define HAVE_RED_MFMA 1
#endif
#if __has_builtin(__builtin_amdgcn_fmed3f)
#define HAVE_MED3 1
#endif
#if __has_builtin(__builtin_amdgcn_exp2f)
#define EXP2R(x) __builtin_amdgcn_exp2f(x)
#else
#define EXP2R(x) __expf((x) * LN2)
#endif
#else
#define EXP2R(x) __expf((x) * LN2)
#endif

#ifdef HAVE_PK_BF16
typedef __bf16 bf16x2 __attribute__((ext_vector_type(2)));
static __device__ __forceinline__ unsigned int pkbf(float a, float b) {
    bf16x2 r = __builtin_amdgcn_cvt_pk_bf16_f32(a, b);
    return __builtin_bit_cast(unsigned int, r);
}
#else
static __device__ __forceinline__ unsigned short f2bf_sw(float f) {
    unsigned int u = __builtin_bit_cast(unsigned int, f);
    u += 0x7fffu + ((u >> 16) & 1u);
    return (unsigned short)(u >> 16);
}
static __device__ __forceinline__ unsigned int pkbf(float a, float b) {
    return (unsigned int)f2bf_sw(a) | ((unsigned int)f2bf_sw(b) << 16);
}
#endif

#ifdef HAVE_RED_MFMA
static __device__ __forceinline__ unsigned pkh(float a, float b) {
    f16x2 h = __builtin_amdgcn_cvt_pkrtz(a, b);
    return __builtin_bit_cast(unsigned, h);
}
static __device__ __forceinline__ f16x4 mkf16x4(unsigned lo, unsigned hi) {
    u32x2 u = {lo, hi};
    return __builtin_bit_cast(f16x4, u);
}
#endif

// elu via med3 (exact): for x>0, {0 < x < e^x-1} -> median x; x<0 -> median e^x-1.
static __device__ __forceinline__ float elu(float x) {
#ifdef HAVE_MED3
    return __builtin_amdgcn_fmed3f(x, __expf(x) - 1.f, 0.f);
#else
    return x > 0.f ? x : __expf(x) - 1.f;
#endif
}

// elu(z)+1 from a LOG2E-PRESCALED pre-activation v = log2e*z: 3 VALU.
//   e^z = exp2(v);  z+1 = fma(v, ln2, 1).  Orderings: z>0: e^z >= z+1 >= 1 ->
//   med = z+1; z<0: z+1 <= e^z <= 1 -> med = e^z. Exact (elu+1).
static __device__ __forceinline__ float elup1s(float v) {
    const float e = EXP2R(v);
    const float t = fmaf(v, LN2, 1.0f);
#ifdef HAVE_MED3
    return __builtin_amdgcn_fmed3f(t, e, 1.0f);
#else
    return v > 0.f ? t : e;
#endif
}

// Async global->LDS DMA, 16B per lane. LDS dest = wave-uniform base + lane*16.
static __device__ __forceinline__ void stage16(const uint4* gsrc_lane, uint4* ldst_base) {
#if defined(__has_builtin) && __has_builtin(__builtin_amdgcn_global_load_lds)
    __builtin_amdgcn_global_load_lds(
        (const __attribute__((address_space(1))) void*)gsrc_lane,
        (__attribute__((address_space(3))) void*)ldst_base, 16, 0, 0);
#else
    ldst_base[threadIdx.x & 63] = *gsrc_lane;
#endif
}

// ---- merged prep ----
// blocks [0,3125):  features1/features2 -> bf16 (8 floats per thread)
// blocks [3125,3253): W^T bf16 images in MFMA FRAGMENT ORDER.
//   W2 (m==1) is PRE-SCALED by log2e so layer-2 pre-activations come out as
//   log2e*h2, feeding the 3-instr elup1s form directly.
__global__ void prep_all(const float* __restrict__ f1, const float* __restrict__ f2,
                         const float* __restrict__ W1, const float* __restrict__ W2,
                         unsigned short* __restrict__ fdst,   // f1b (f2b follows)
                         unsigned short* __restrict__ wsW) {
    const int blk = blockIdx.x;
    if (blk < 3125) {
        const int g = blk * 256 + threadIdx.x;                // 0 .. 799999
        const size_t base = (size_t)g * 8;
        const float* src = (base < FELEMS) ? (f1 + base) : (f2 + base - FELEMS);
        const float4 v0 = *(const float4*)src;
        const float4 v1 = *(const float4*)(src + 4);
        uint4 o;
        o.x = pkbf(v0.x, v0.y);
        o.y = pkbf(v0.z, v0.w);
        o.z = pkbf(v1.x, v1.y);
        o.w = pkbf(v1.z, v1.w);
        *(uint4*)(fdst + base) = o;
    } else {
        const int idx  = (blk - 3125) * 256 + threadIdx.x;    // 0 .. 32767
        const int m    = idx >> 14;
        const int o    = idx & 16383;
        const int j    = o & 7;
        const int lane = (o >> 3) & 63;
        const int ksmt = o >> 9;         // mt*4 + ks
        const int ks   = ksmt & 3;
        const int mt   = ksmt >> 2;
        const int d = mt * 16 + (lane & 15);
        const int k = ks * 32 + (lane >> 4) * 8 + j;
        const float* W = m ? W2 : W1;
        const float scale = m ? LOG2E : 1.0f;
        wsW[idx] = (unsigned short)pkbf(W[(size_t)k * NDC + d] * scale, 0.f);
    }
}

// ONE TILE PER BLOCK (grid 3125). The r4-r6 persistent variants all spilled to
// scratch (0.3-1.2 GB of parasitic HBM traffic, 5x slowdown): this straight-line
// body fits the 128-reg/wave cap EXACTLY (64 VGPR + 64 acc) and any loop-carried
// persistent state pushed it over. Do not reintroduce a tile loop without first
// shrinking P's live range.
__global__ __launch_bounds__(512, 4)
void fused_knn_mlp(const unsigned short* __restrict__ f1b,
                   const unsigned short* __restrict__ f2b,
                   const float* __restrict__ x1,
                   const float* __restrict__ x2,
                   const int*   __restrict__ topk,
                   const float* __restrict__ b1,
                   const float* __restrict__ b2,
                   const float* __restrict__ radius,
                   const unsigned short* __restrict__ wsW,
                   float* __restrict__ out)
{
    // W1 frags in chunks [0,2048), W2' (log2e-scaled) frags in [2048,4096).
    // 64 KB -> 2 blocks/CU, 16 waves/CU; single barrier per block.
    __shared__ uint4 sW[4096];   // 64 KB

    const int tid  = threadIdx.x;
    const int blk  = blockIdx.x;
    const int lane = tid & 63;
    const int wave = tid >> 6;          // 0..7
    const int quad = lane >> 4;
    const int l16  = lane & 15;
    const int rloc = wave * 32 + l16;   // this lane's row0 within the block (row1 = +16)

    const uint4* wp = (const uint4*)wsW;   // 4096 chunks (W1 then W2', frag order)

    // ---- W1+W2 DMA into LDS: zero VGPRs, async (drained by the barrier) ----
    #pragma unroll
    for (int it = 0; it < 8; ++it) {
        const int base = wave * 512 + it * 64;
        stage16(wp + base + lane, sW + base);
    }

    // ---- this lane's two rows + X B-frags (direct global gather, overlaps DMA) ----
    const int idx0 = topk[blk * MR + rloc];
    const int idx1 = topk[blk * MR + rloc + 16];
    const int q0   = blk * QB + wave * 2;
    const int q1   = q0 + 1;

    // k 0..63 = features2[idx] (neighbor), k 64..127 = features1[q] (self) — reference concat order.
    uint4 xf0[4], xf1[4];
    #pragma unroll
    for (int ks = 0; ks < 2; ++ks) {
        xf0[ks] = *(const uint4*)(f2b + (size_t)idx0 * NIC + ks * 32 + quad * 8);
        xf1[ks] = *(const uint4*)(f2b + (size_t)idx1 * NIC + ks * 32 + quad * 8);
        xf0[ks + 2] = *(const uint4*)(f1b + (size_t)q0 * NIC + ks * 32 + quad * 8);
        xf1[ks + 2] = *(const uint4*)(f1b + (size_t)q1 * NIC + ks * 32 + quad * 8);
    }

    // ---- distance weights for rows r0, r1 ----
    float wg0, wg1;
    {
        const float rr = radius[0];
        const float inv2r2 = 1.f / (2.f * rr * rr);
        const float dx0 = x2[idx0 * 3 + 0] - x1[q0 * 3 + 0];
        const float dy0 = x2[idx0 * 3 + 1] - x1[q0 * 3 + 1];
        const float dz0 = x2[idx0 * 3 + 2] - x1[q0 * 3 + 2];
        const float dx1 = x2[idx1 * 3 + 0] - x1[q1 * 3 + 0];
        const float dy1 = x2[idx1 * 3 + 1] - x1[q1 * 3 + 1];
        const float dz1 = x2[idx1 * 3 + 2] - x1[q1 * 3 + 2];
        wg0 = (idx0 == 0) ? 0.f : __expf(-(dx0 * dx0 + dy0 * dy0 + dz0 * dz0) * inv2r2);
        wg1 = (idx1 == 0) ? 0.f : __expf(-(dx1 * dx1 + dy1 * dy1 + dz1 * dz1) * inv2r2);
    }

    __syncthreads();   // W1+W2 DMA drained (vmcnt) + all waves ready — the ONLY barrier

    // ---- layer 1 (swapped): D1[d1][r] = sum_k W1T[d1][k] * X[r][k] ----
    // BIAS-IN-ACCUMULATOR: acc init = b1 fragment (C row = d1 = quad*4+reg).
    // Lane (quad,l16) of P holds h1[r = wave*32 + nt*16 + l16][d = mt*16 + quad*4 + reg]
    unsigned P[8][2][2];
    #pragma unroll
    for (int mp = 0; mp < 4; ++mp) {
        f32x4 accp[2][2];   // [mt within pair][row tile]
        #pragma unroll
        for (int mi = 0; mi < 2; ++mi) {
            const float4 b1v = *(const float4*)(b1 + (mp * 2 + mi) * 16 + quad * 4);
            accp[mi][0] = (f32x4){b1v.x, b1v.y, b1v.z, b1v.w};
            accp[mi][1] = accp[mi][0];
        }
        #pragma unroll
        for (int ks = 0; ks < 4; ++ks) {
            const bf16x8 x0  = __builtin_bit_cast(bf16x8, xf0[ks]);
            const bf16x8 x1v = __builtin_bit_cast(bf16x8, xf1[ks]);
            #pragma unroll
            for (int mi = 0; mi < 2; ++mi) {
                const int mt = mp * 2 + mi;
                const bf16x8 a = *(const bf16x8*)&sW[(mt * 4 + ks) * 64 + lane];
                accp[mi][0] = __builtin_amdgcn_mfma_f32_16x16x32_bf16(a, x0,  accp[mi][0], 0, 0, 0);
                accp[mi][1] = __builtin_amdgcn_mfma_f32_16x16x32_bf16(a, x1v, accp[mi][1], 0, 0, 0);
            }
        }
        #pragma unroll
        for (int mi = 0; mi < 2; ++mi) {
            const int mt = mp * 2 + mi;
            #pragma unroll
            for (int nt = 0; nt < 2; ++nt) {
                P[mt][nt][0] = pkbf(elu(accp[mi][nt][0]), elu(accp[mi][nt][1]));
                P[mt][nt][1] = pkbf(elu(accp[mi][nt][2]), elu(accp[mi][nt][3]));
            }
        }
    }

    // ---- layer 2: acc2 = log2e * (W2T h1 + b2)  (W2' prescaled; b2 scaled here) ----
    // BIAS-IN-ACCUMULATOR: acc2 init = log2e*b2[d2] (C col = l16).
    f32x4 acc2[2][8];
    #pragma unroll
    for (int nt2 = 0; nt2 < 8; ++nt2) {
        const float bb = LOG2E * b2[nt2 * 16 + l16];
        acc2[0][nt2] = (f32x4){bb, bb, bb, bb};
        acc2[1][nt2] = acc2[0][nt2];
    }
    const bool qodd = (quad & 1) != 0;
    #pragma unroll
    for (int ks = 0; ks < 4; ++ks) {
        u32x4 a2[2];
        #pragma unroll
        for (int mt2 = 0; mt2 < 2; ++mt2) {
#ifdef HAVE_PL32
            // A-frag transpose via permlane32_swap + xor-16 exchange (verified r3-r8).
            #pragma unroll
            for (int e = 0; e < 2; ++e) {
                auto pr = __builtin_amdgcn_permlane32_swap(
                    P[2 * ks][mt2][e], P[2 * ks + 1][mt2][e], false, false);
                const unsigned Rv = qodd ? (unsigned)pr[1] : (unsigned)pr[0];
                const unsigned Zv = qodd ? (unsigned)pr[0] : (unsigned)pr[1];
                const unsigned Sv = __shfl_xor(Zv, 16, 64);
                a2[mt2][e]     = qodd ? Sv : Rv;
                a2[mt2][2 + e] = qodd ? Rv : Sv;
            }
#else
            #pragma unroll
            for (int u = 0; u < 4; ++u) {
                const int src = (((quad * 2) + (u >> 1)) & 3) * 16 + l16;
                const unsigned lo = __shfl(P[2 * ks][mt2][u & 1], src, 64);
                const unsigned hi = __shfl(P[2 * ks + 1][mt2][u & 1], src, 64);
                a2[mt2][u] = (quad & 2) ? hi : lo;
            }
#endif
        }
        const bf16x8 af0 = __builtin_bit_cast(bf16x8, a2[0]);
        const bf16x8 af1 = __builtin_bit_cast(bf16x8, a2[1]);
        #pragma unroll
        for (int nt2 = 0; nt2 < 8; ++nt2) {
            const bf16x8 b = *(const bf16x8*)&sW[2048 + (nt2 * 4 + ks) * 64 + lane];
            acc2[0][nt2] = __builtin_amdgcn_mfma_f32_16x16x32_bf16(af0, b, acc2[0][nt2], 0, 0, 0);
            acc2[1][nt2] = __builtin_amdgcn_mfma_f32_16x16x32_bf16(af1, b, acc2[1][nt2], 0, 0, 0);
        }
    }

    // ---- epilogue: out[q][d2] = sum_n w_n*elu(h2) = sum_n w_n*(elu+1) - sum_n w_n ----
    // acc2 row = quad*4+reg (neighbor within query), col = l16 (d2 within nt2 tile)
    const size_t ob = (size_t)(blk * QB + wave * 2) * NDC;
#ifdef HAVE_RED_MFMA
    // f16 reduction MFMA (verified r4-r8): acc2's C-layout IS the f16 B-frag
    // layout for 16x16x16 — zero shuffles. m-form elu (elup1s, 3 VALU) with the
    // "-sum(w)" correction injected FREE via C = mfma(aw, -ones, 0).
    float w0j[4], w1j[4];
    #pragma unroll
    for (int j = 0; j < 4; ++j) {
        w0j[j] = __shfl(wg0, quad * 4 + j, 64);
        w1j[j] = __shfl(wg1, quad * 4 + j, 64);
    }
    const f16x4 aw0 = mkf16x4(pkh(w0j[0], w0j[1]), pkh(w0j[2], w0j[3]));
    const f16x4 aw1 = mkf16x4(pkh(w1j[0], w1j[1]), pkh(w1j[2], w1j[3]));
    const f32x4 zero4 = {0.f, 0.f, 0.f, 0.f};
    const f16x4 negones = mkf16x4(0xBC00BC00u, 0xBC00BC00u);   // f16 -1.0 x4
    // C0/C1: every entry = -sum_n w_n (A rows identical => D uniform).
    const f32x4 c0 = __builtin_amdgcn_mfma_f32_16x16x16f16(aw0, negones, zero4, 0, 0, 0);
    const f32x4 c1 = __builtin_amdgcn_mfma_f32_16x16x16f16(aw1, negones, zero4, 0, 0, 0);
    #pragma unroll
    for (int nt2 = 0; nt2 < 8; ++nt2) {
        const f16x4 be0 = mkf16x4(pkh(elup1s(acc2[0][nt2][0]), elup1s(acc2[0][nt2][1])),
                                  pkh(elup1s(acc2[0][nt2][2]), elup1s(acc2[0][nt2][3])));
        const f16x4 be1 = mkf16x4(pkh(elup1s(acc2[1][nt2][0]), elup1s(acc2[1][nt2][1])),
                                  pkh(elup1s(acc2[1][nt2][2]), elup1s(acc2[1][nt2][3])));
        const f32x4 d0 = __builtin_amdgcn_mfma_f32_16x16x16f16(aw0, be0, c0, 0, 0, 0);
        const f32x4 d1 = __builtin_amdgcn_mfma_f32_16x16x16f16(aw1, be1, c1, 0, 0, 0);
        if (quad == 0) {
            out[ob + nt2 * 16 + l16] = d0[0];
            out[ob + NDC + nt2 * 16 + l16] = d1[0];
        }
    }
#else
    float wk0[4], wk1[4];
    #pragma unroll
    for (int reg = 0; reg < 4; ++reg) {
        const int src = (lane & 48) | (quad * 4 + reg);
        wk0[reg] = __shfl(wg0, src, 64);
        wk1[reg] = __shfl(wg1, src, 64);
    }
    #pragma unroll
    for (int mt2 = 0; mt2 < 2; ++mt2) {
        #pragma unroll
        for (int nt2 = 0; nt2 < 8; ++nt2) {
            const int d2 = nt2 * 16 + l16;
            float s;
            if (mt2 == 0)
                s = (elup1s(acc2[0][nt2][0]) - 1.f) * wk0[0] + (elup1s(acc2[0][nt2][1]) - 1.f) * wk0[1]
                  + (elup1s(acc2[0][nt2][2]) - 1.f) * wk0[2] + (elup1s(acc2[0][nt2][3]) - 1.f) * wk0[3];
            else
                s = (elup1s(acc2[1][nt2][0]) - 1.f) * wk1[0] + (elup1s(acc2[1][nt2][1]) - 1.f) * wk1[1]
                  + (elup1s(acc2[1][nt2][2]) - 1.f) * wk1[2] + (elup1s(acc2[1][nt2][3]) - 1.f) * wk1[3];
            s += __shfl_xor(s, 16, 64);
            s += __shfl_xor(s, 32, 64);
            if (lane < 16) {
                out[ob + mt2 * NDC + d2] = s;
            }
        }
    }
#endif
}

extern "C" void kernel_launch(void* const* d_in, const int* in_sizes, int n_in,
                              void* d_out, int out_size, void* d_ws, size_t ws_size,
                              hipStream_t stream) {
    const float* features1 = (const float*)d_in[0];
    const float* features2 = (const float*)d_in[1];
    const float* x1        = (const float*)d_in[2];
    const float* x2        = (const float*)d_in[3];
    // d_in[4], d_in[5] = nuv1, nuv2 (unused by reference)
    const int*   topk      = (const int*)d_in[6];
    const float* W1        = (const float*)d_in[7];
    const float* b1        = (const float*)d_in[8];
    const float* W2        = (const float*)d_in[9];
    const float* b2        = (const float*)d_in[10];
    const float* radius    = (const float*)d_in[11];
    float* out = (float*)d_out;

    unsigned short* wsW = (unsigned short*)d_ws;      // 32768 shorts = 64 KB (frag-order W1, W2')
    unsigned short* f1b = wsW + 32768;                // 3.2M shorts
    unsigned short* f2b = f1b + FELEMS;               // 3.2M shorts

    prep_all<<<dim3(3253), 256, 0, stream>>>(features1, features2, W1, W2, f1b, wsW);
    fused_knn_mlp<<<dim3(N1C / QB), 512, 0, stream>>>(f1b, f2b, x1, x2, topk,
                                                      b1, b2, radius, wsW, out);
}

// Round 10
// 177.900 us; speedup vs baseline: 1.0494x; 1.0494x over previous
//
#include <hip/hip_runtime.h>

// Problem constants (from reference)
#define N1C 50000
#define N2C 50000
#define NNC 16
#define NIC 64
#define NDC 128
#define QB  16       // queries per block (16 queries x 16 neighbors = 256 rows)
#define MR  256      // QB*NN rows per block
#define FELEMS (N1C * NIC)   // 3.2M elements per feature array

typedef __bf16 bf16x8 __attribute__((ext_vector_type(8)));
typedef float f32x4 __attribute__((ext_vector_type(4)));
typedef unsigned u32x4 __attribute__((ext_vector_type(4)));
typedef unsigned u32x2 __attribute__((ext_vector_type(2)));
typedef __fp16 f16x4 __attribute__((ext_vector_type(4)));
typedef __fp16 f16x2 __attribute__((ext_vector_type(2)));

#if defined(__has_builtin)
#if __has_builtin(__builtin_amdgcn_cvt_pk_bf16_f32)
#define HAVE_PK_BF16 1
#endif
#if __has_builtin(__builtin_amdgcn_permlane32_swap)
#define HAVE_PL32 1
#endif
#if __has_builtin(__builtin_amdgcn_mfma_f32_16x16x16f16) && __has_builtin(__builtin_amdgcn_cvt_pkrtz)
#define HAVE_RED_MFMA 1
#endif
#if __has_builtin(__builtin_amdgcn_fmed3f)
#define HAVE_MED3 1
#endif
#endif

#ifdef HAVE_PK_BF16
typedef __bf16 bf16x2 __attribute__((ext_vector_type(2)));
static __device__ __forceinline__ unsigned int pkbf(float a, float b) {
    bf16x2 r = __builtin_amdgcn_cvt_pk_bf16_f32(a, b);
    return __builtin_bit_cast(unsigned int, r);
}
#else
static __device__ __forceinline__ unsigned short f2bf_sw(float f) {
    unsigned int u = __builtin_bit_cast(unsigned int, f);
    u += 0x7fffu + ((u >> 16) & 1u);
    return (unsigned short)(u >> 16);
}
static __device__ __forceinline__ unsigned int pkbf(float a, float b) {
    return (unsigned int)f2bf_sw(a) | ((unsigned int)f2bf_sw(b) << 16);
}
#endif

#ifdef HAVE_RED_MFMA
static __device__ __forceinline__ unsigned pkh(float a, float b) {
    f16x2 h = __builtin_amdgcn_cvt_pkrtz(a, b);
    return __builtin_bit_cast(unsigned, h);
}
static __device__ __forceinline__ f16x4 mkf16x4(unsigned lo, unsigned hi) {
    u32x2 u = {lo, hi};
    return __builtin_bit_cast(f16x4, u);
}
#endif

// elu via med3: for x>0, {0 < x < e^x-1} -> median x; for x<0, {x < e^x-1 < 0}
// -> median e^x-1. Bit-identical to the ternary, one instr fewer, no vcc dep.
static __device__ __forceinline__ float elu(float x) {
#ifdef HAVE_MED3
    return __builtin_amdgcn_fmed3f(x, __expf(x) - 1.f, 0.f);
#else
    return x > 0.f ? x : __expf(x) - 1.f;
#endif
}

// Async global->LDS DMA, 16B per lane. LDS dest = wave-uniform base + lane*16.
static __device__ __forceinline__ void stage16(const uint4* gsrc_lane, uint4* ldst_base) {
#if defined(__has_builtin) && __has_builtin(__builtin_amdgcn_global_load_lds)
    __builtin_amdgcn_global_load_lds(
        (const __attribute__((address_space(1))) void*)gsrc_lane,
        (__attribute__((address_space(3))) void*)ldst_base, 16, 0, 0);
#else
    ldst_base[threadIdx.x & 63] = *gsrc_lane;
#endif
}

// ---- merged prep ----
// blocks [0,3125):  features1/features2 -> bf16 (8 floats per thread)
// blocks [3125,3253): W^T bf16 images in MFMA FRAGMENT ORDER
//   chunk ((mt*4+ks)*64+lane), 8 shorts/chunk: W^T[d=mt*16+(lane&15)][k=ks*32+(lane>>4)*8+j]
__global__ void prep_all(const float* __restrict__ f1, const float* __restrict__ f2,
                         const float* __restrict__ W1, const float* __restrict__ W2,
                         unsigned short* __restrict__ fdst,   // f1b (f2b follows)
                         unsigned short* __restrict__ wsW) {
    const int blk = blockIdx.x;
    if (blk < 3125) {
        const int g = blk * 256 + threadIdx.x;                // 0 .. 799999
        const size_t base = (size_t)g * 8;
        const float* src = (base < FELEMS) ? (f1 + base) : (f2 + base - FELEMS);
        const float4 v0 = *(const float4*)src;
        const float4 v1 = *(const float4*)(src + 4);
        uint4 o;
        o.x = pkbf(v0.x, v0.y);
        o.y = pkbf(v0.z, v0.w);
        o.z = pkbf(v1.x, v1.y);
        o.w = pkbf(v1.z, v1.w);
        *(uint4*)(fdst + base) = o;
    } else {
        const int idx  = (blk - 3125) * 256 + threadIdx.x;    // 0 .. 32767
        const int m    = idx >> 14;
        const int o    = idx & 16383;
        const int j    = o & 7;
        const int lane = (o >> 3) & 63;
        const int ksmt = o >> 9;         // mt*4 + ks
        const int ks   = ksmt & 3;
        const int mt   = ksmt >> 2;
        const int d = mt * 16 + (lane & 15);
        const int k = ks * 32 + (lane >> 4) * 8 + j;
        const float* W = m ? W2 : W1;
        wsW[idx] = (unsigned short)pkbf(W[(size_t)k * NDC + d], 0.f);
    }
}

// ONE TILE PER BLOCK (grid 3125). REGISTER-CAP NOTE (r4-r6, r9 lessons): this
// straight-line body sits EXACTLY at the 128-reg/wave cap (64 VGPR + 64 acc,
// 16 waves/CU). Persistent-loop state (r4/r5/r6: +0.3-1.2 GB scratch traffic,
// 5x slowdown) AND even +8 regs of epilogue state (r9: c0/c1 correction frags,
// +28 MB spill writes, -7%) push it over. Do not add ANY live state.
__global__ __launch_bounds__(512, 4)
void fused_knn_mlp(const unsigned short* __restrict__ f1b,
                   const unsigned short* __restrict__ f2b,
                   const float* __restrict__ x1,
                   const float* __restrict__ x2,
                   const int*   __restrict__ topk,
                   const float* __restrict__ b1,
                   const float* __restrict__ b2,
                   const float* __restrict__ radius,
                   const unsigned short* __restrict__ wsW,
                   float* __restrict__ out)
{
    // W1 frags in chunks [0,2048), W2 frags in [2048,4096). 64 KB -> 2 blocks/CU,
    // 16 waves/CU; single barrier per block.
    __shared__ uint4 sW[4096];   // 64 KB

    const int tid  = threadIdx.x;
    const int blk  = blockIdx.x;
    const int lane = tid & 63;
    const int wave = tid >> 6;          // 0..7
    const int quad = lane >> 4;
    const int l16  = lane & 15;
    const int rloc = wave * 32 + l16;   // this lane's row0 within the block (row1 = +16)

    const uint4* wp = (const uint4*)wsW;   // 4096 chunks (W1 then W2, frag order)

    // ---- W1+W2 DMA into LDS: zero VGPRs, async (drained by the barrier) ----
    #pragma unroll
    for (int it = 0; it < 8; ++it) {
        const int base = wave * 512 + it * 64;
        stage16(wp + base + lane, sW + base);
    }

    // ---- this lane's two rows + X B-frags (direct global gather, overlaps DMA) ----
    const int idx0 = topk[blk * MR + rloc];
    const int idx1 = topk[blk * MR + rloc + 16];
    const int q0   = blk * QB + wave * 2;
    const int q1   = q0 + 1;

    // k 0..63 = features2[idx] (neighbor), k 64..127 = features1[q] (self) — reference concat order.
    uint4 xf0[4], xf1[4];
    #pragma unroll
    for (int ks = 0; ks < 2; ++ks) {
        xf0[ks] = *(const uint4*)(f2b + (size_t)idx0 * NIC + ks * 32 + quad * 8);
        xf1[ks] = *(const uint4*)(f2b + (size_t)idx1 * NIC + ks * 32 + quad * 8);
        xf0[ks + 2] = *(const uint4*)(f1b + (size_t)q0 * NIC + ks * 32 + quad * 8);
        xf1[ks + 2] = *(const uint4*)(f1b + (size_t)q1 * NIC + ks * 32 + quad * 8);
    }

    // ---- distance weights for rows r0, r1 ----
    float wg0, wg1;
    {
        const float rr = radius[0];
        const float inv2r2 = 1.f / (2.f * rr * rr);
        const float dx0 = x2[idx0 * 3 + 0] - x1[q0 * 3 + 0];
        const float dy0 = x2[idx0 * 3 + 1] - x1[q0 * 3 + 1];
        const float dz0 = x2[idx0 * 3 + 2] - x1[q0 * 3 + 2];
        const float dx1 = x2[idx1 * 3 + 0] - x1[q1 * 3 + 0];
        const float dy1 = x2[idx1 * 3 + 1] - x1[q1 * 3 + 1];
        const float dz1 = x2[idx1 * 3 + 2] - x1[q1 * 3 + 2];
        wg0 = (idx0 == 0) ? 0.f : __expf(-(dx0 * dx0 + dy0 * dy0 + dz0 * dz0) * inv2r2);
        wg1 = (idx1 == 0) ? 0.f : __expf(-(dx1 * dx1 + dy1 * dy1 + dz1 * dz1) * inv2r2);
    }

    __syncthreads();   // W1+W2 DMA drained (vmcnt) + all waves ready — the ONLY barrier

    // ---- layer 1 (swapped): D1[d1][r] = sum_k W1T[d1][k] * X[r][k] ----
    // BIAS-IN-ACCUMULATOR: acc init = b1 fragment (C row = d1 = quad*4+reg).
    // Lane (quad,l16) of P holds h1[r = wave*32 + nt*16 + l16][d = mt*16 + quad*4 + reg]
    unsigned P[8][2][2];
    #pragma unroll
    for (int mp = 0; mp < 4; ++mp) {
        f32x4 accp[2][2];   // [mt within pair][row tile]
        #pragma unroll
        for (int mi = 0; mi < 2; ++mi) {
            const float4 b1v = *(const float4*)(b1 + (mp * 2 + mi) * 16 + quad * 4);
            accp[mi][0] = (f32x4){b1v.x, b1v.y, b1v.z, b1v.w};
            accp[mi][1] = accp[mi][0];
        }
        #pragma unroll
        for (int ks = 0; ks < 4; ++ks) {
            const bf16x8 x0  = __builtin_bit_cast(bf16x8, xf0[ks]);
            const bf16x8 x1v = __builtin_bit_cast(bf16x8, xf1[ks]);
            #pragma unroll
            for (int mi = 0; mi < 2; ++mi) {
                const int mt = mp * 2 + mi;
                const bf16x8 a = *(const bf16x8*)&sW[(mt * 4 + ks) * 64 + lane];
                accp[mi][0] = __builtin_amdgcn_mfma_f32_16x16x32_bf16(a, x0,  accp[mi][0], 0, 0, 0);
                accp[mi][1] = __builtin_amdgcn_mfma_f32_16x16x32_bf16(a, x1v, accp[mi][1], 0, 0, 0);
            }
        }
        #pragma unroll
        for (int mi = 0; mi < 2; ++mi) {
            const int mt = mp * 2 + mi;
            #pragma unroll
            for (int nt = 0; nt < 2; ++nt) {
                P[mt][nt][0] = pkbf(elu(accp[mi][nt][0]), elu(accp[mi][nt][1]));
                P[mt][nt][1] = pkbf(elu(accp[mi][nt][2]), elu(accp[mi][nt][3]));
            }
        }
    }

    // ---- layer 2: D2[r][d2] = sum_d h1[r][d] * W2T[d2][d] ----
    // BIAS-IN-ACCUMULATOR: acc2 init = b2[d2] (C col = l16; same value on all 4 regs).
    f32x4 acc2[2][8];
    #pragma unroll
    for (int nt2 = 0; nt2 < 8; ++nt2) {
        const float bb = b2[nt2 * 16 + l16];
        acc2[0][nt2] = (f32x4){bb, bb, bb, bb};
        acc2[1][nt2] = acc2[0][nt2];
    }
    const bool qodd = (quad & 1) != 0;
    #pragma unroll
    for (int ks = 0; ks < 4; ++ks) {
        u32x4 a2[2];
        #pragma unroll
        for (int mt2 = 0; mt2 < 2; ++mt2) {
#ifdef HAVE_PL32
            // A-frag transpose via permlane32_swap + xor-16 exchange (verified r3-r9).
            #pragma unroll
            for (int e = 0; e < 2; ++e) {
                auto pr = __builtin_amdgcn_permlane32_swap(
                    P[2 * ks][mt2][e], P[2 * ks + 1][mt2][e], false, false);
                const unsigned Rv = qodd ? (unsigned)pr[1] : (unsigned)pr[0];
                const unsigned Zv = qodd ? (unsigned)pr[0] : (unsigned)pr[1];
                const unsigned Sv = __shfl_xor(Zv, 16, 64);
                a2[mt2][e]     = qodd ? Sv : Rv;
                a2[mt2][2 + e] = qodd ? Rv : Sv;
            }
#else
            #pragma unroll
            for (int u = 0; u < 4; ++u) {
                const int src = (((quad * 2) + (u >> 1)) & 3) * 16 + l16;
                const unsigned lo = __shfl(P[2 * ks][mt2][u & 1], src, 64);
                const unsigned hi = __shfl(P[2 * ks + 1][mt2][u & 1], src, 64);
                a2[mt2][u] = (quad & 2) ? hi : lo;
            }
#endif
        }
        const bf16x8 af0 = __builtin_bit_cast(bf16x8, a2[0]);
        const bf16x8 af1 = __builtin_bit_cast(bf16x8, a2[1]);
        #pragma unroll
        for (int nt2 = 0; nt2 < 8; ++nt2) {
            const bf16x8 b = *(const bf16x8*)&sW[2048 + (nt2 * 4 + ks) * 64 + lane];
            acc2[0][nt2] = __builtin_amdgcn_mfma_f32_16x16x32_bf16(af0, b, acc2[0][nt2], 0, 0, 0);
            acc2[1][nt2] = __builtin_amdgcn_mfma_f32_16x16x32_bf16(af1, b, acc2[1][nt2], 0, 0, 0);
        }
    }

    // ---- epilogue: out[q][d2] = sum_n w_n * elu(h2[n][d2]) ----  (bias already in acc)
    // acc2 row = quad*4+reg (neighbor within query), col = l16 (d2 within nt2 tile)
    const size_t ob = (size_t)(blk * QB + wave * 2) * NDC;
#ifdef HAVE_RED_MFMA
    // f16 reduction MFMA (verified on HW r4-r9, absmax 0.125): acc2's C-layout IS
    // the f16 B-frag layout for 16x16x16 (B[k=quad*4+j][col=l16]) — zero shuffles.
    // w enters as a row-broadcast A-frag built HERE (after L2) so register
    // liveness through the MFMA loops matches the proven r3 allocation.
    float w0j[4], w1j[4];
    #pragma unroll
    for (int j = 0; j < 4; ++j) {
        w0j[j] = __shfl(wg0, quad * 4 + j, 64);
        w1j[j] = __shfl(wg1, quad * 4 + j, 64);
    }
    const f16x4 aw0 = mkf16x4(pkh(w0j[0], w0j[1]), pkh(w0j[2], w0j[3]));
    const f16x4 aw1 = mkf16x4(pkh(w1j[0], w1j[1]), pkh(w1j[2], w1j[3]));
    const f32x4 zero4 = {0.f, 0.f, 0.f, 0.f};
    #pragma unroll
    for (int nt2 = 0; nt2 < 8; ++nt2) {
        const f16x4 be0 = mkf16x4(pkh(elu(acc2[0][nt2][0]), elu(acc2[0][nt2][1])),
                                  pkh(elu(acc2[0][nt2][2]), elu(acc2[0][nt2][3])));
        const f16x4 be1 = mkf16x4(pkh(elu(acc2[1][nt2][0]), elu(acc2[1][nt2][1])),
                                  pkh(elu(acc2[1][nt2][2]), elu(acc2[1][nt2][3])));
        const f32x4 d0 = __builtin_amdgcn_mfma_f32_16x16x16f16(aw0, be0, zero4, 0, 0, 0);
        const f32x4 d1 = __builtin_amdgcn_mfma_f32_16x16x16f16(aw1, be1, zero4, 0, 0, 0);
        if (quad == 0) {
            out[ob + nt2 * 16 + l16] = d0[0];
            out[ob + NDC + nt2 * 16 + l16] = d1[0];
        }
    }
#else
    float wk0[4], wk1[4];
    #pragma unroll
    for (int reg = 0; reg < 4; ++reg) {
        const int src = (lane & 48) | (quad * 4 + reg);
        wk0[reg] = __shfl(wg0, src, 64);
        wk1[reg] = __shfl(wg1, src, 64);
    }
    #pragma unroll
    for (int mt2 = 0; mt2 < 2; ++mt2) {
        #pragma unroll
        for (int nt2 = 0; nt2 < 8; ++nt2) {
            const int d2 = nt2 * 16 + l16;
            float s;
            if (mt2 == 0)
                s = elu(acc2[0][nt2][0]) * wk0[0] + elu(acc2[0][nt2][1]) * wk0[1]
                  + elu(acc2[0][nt2][2]) * wk0[2] + elu(acc2[0][nt2][3]) * wk0[3];
            else
                s = elu(acc2[1][nt2][0]) * wk1[0] + elu(acc2[1][nt2][1]) * wk1[1]
                  + elu(acc2[1][nt2][2]) * wk1[2] + elu(acc2[1][nt2][3]) * wk1[3];
            s += __shfl_xor(s, 16, 64);
            s += __shfl_xor(s, 32, 64);
            if (lane < 16) {
                out[ob + mt2 * NDC + d2] = s;
            }
        }
    }
#endif
}

extern "C" void kernel_launch(void* const* d_in, const int* in_sizes, int n_in,
                              void* d_out, int out_size, void* d_ws, size_t ws_size,
                              hipStream_t stream) {
    const float* features1 = (const float*)d_in[0];
    const float* features2 = (const float*)d_in[1];
    const float* x1        = (const float*)d_in[2];
    const float* x2        = (const float*)d_in[3];
    // d_in[4], d_in[5] = nuv1, nuv2 (unused by reference)
    const int*   topk      = (const int*)d_in[6];
    const float* W1        = (const float*)d_in[7];
    const float* b1        = (const float*)d_in[8];
    const float* W2        = (const float*)d_in[9];
    const float* b2        = (const float*)d_in[10];
    const float* radius    = (const float*)d_in[11];
    float* out = (float*)d_out;

    unsigned short* wsW = (unsigned short*)d_ws;      // 32768 shorts = 64 KB (frag-order W1,W2)
    unsigned short* f1b = wsW + 32768;                // 3.2M shorts
    unsigned short* f2b = f1b + FELEMS;               // 3.2M shorts

    prep_all<<<dim3(3253), 256, 0, stream>>>(features1, features2, W1, W2, f1b, wsW);
    fused_knn_mlp<<<dim3(N1C / QB), 512, 0, stream>>>(f1b, f2b, x1, x2, topk,
                                                      b1, b2, radius, wsW, out);
}